// Round 10
// baseline (310.493 us; speedup 1.0000x reference)
//
#include <hip/hip_runtime.h>

#define NN 100000
#define NE 1600000
#define NCAP 64             // per-node slab capacity (incl. self); deg ~ Poisson(16)
#define NB 391              // slab blocks: buckets of 256 dst nodes
#define NBK 512             // padded bucket count (256-node buckets)
#define CAPG 768            // per-(grp,bucket) capacity: mean 512, sigma~23 -> 11 sigma
#define CHUNK 2048
#define NCHUNK 782          // ceil(NE/CHUNK)

typedef __attribute__((ext_vector_type(8))) short short8;   // 8 bf16 (4 VGPRs)
typedef __attribute__((ext_vector_type(4))) float f32x4;    // MFMA 16x16 accumulator

static __device__ __forceinline__ unsigned short f2bf(float f) {
    unsigned u = __float_as_uint(f);
    u += 0x7fffu + ((u >> 16) & 1u);   // RNE
    return (unsigned short)(u >> 16);
}
static __device__ __forceinline__ float bflo(unsigned u) { return __uint_as_float(u << 16); }
static __device__ __forceinline__ float bfhi(unsigned u) { return __uint_as_float(u & 0xffff0000u); }

static __device__ __forceinline__ short8 as_s8(uint4 u) {
    union { uint4 u4; short8 s8; } x; x.u4 = u; return x.s8;
}
static __device__ __forceinline__ f32x4 mfma16(short8 a, short8 b, f32x4 c) {
    return __builtin_amdgcn_mfma_f32_16x16x32_bf16(a, b, c, 0, 0, 0);
}

// split 8 fp32 into hi/lo bf16x8 fragments (hi = RNE(v), lo = RNE(v - hi))
static __device__ __forceinline__ void split8(float4 a, float4 b, short8& hi8, short8& lo8) {
    float vv[8] = {a.x, a.y, a.z, a.w, b.x, b.y, b.z, b.w};
    unsigned h[8], l[8];
    #pragma unroll
    for (int j = 0; j < 8; ++j) {
        h[j] = f2bf(vv[j]);
        l[j] = f2bf(vv[j] - bflo(h[j]));
    }
    uint4 uh, ul;
    uh.x = h[0] | (h[1] << 16); uh.y = h[2] | (h[3] << 16);
    uh.z = h[4] | (h[5] << 16); uh.w = h[6] | (h[7] << 16);
    ul.x = l[0] | (l[1] << 16); ul.y = l[2] | (l[3] << 16);
    ul.z = l[4] | (l[5] << 16); ul.w = l[6] | (l[7] << 16);
    hi8 = as_s8(uh); lo8 = as_s8(ul);
}

// ---------------- CSR build phase A (unchanged from R9) ----------------
__global__ __launch_bounds__(256) void bin_edges(const int* __restrict__ src,
                                                 const int* __restrict__ dst,
                                                 int* __restrict__ gcur,
                                                 int* __restrict__ pairs) {
    __shared__ int lcnt[NBK];
    __shared__ int lnext[NBK];
    int t = threadIdx.x;
    int grp = blockIdx.x & 7;
    lcnt[t] = 0; lcnt[t + 256] = 0;
    __syncthreads();
    int base = blockIdx.x * CHUNK;
    int sr[8], dr[8];
    #pragma unroll
    for (int i = 0; i < 8; ++i) {
        int e = base + t + 256 * i;
        bool v = e < NE;
        sr[i] = v ? src[e] : 0;
        dr[i] = v ? dst[e] : -1;
        if (v) atomicAdd(&lcnt[dr[i] >> 8], 1);
    }
    __syncthreads();
    #pragma unroll
    for (int i = 0; i < 2; ++i) {
        int b = t + 256 * i;
        int v = lcnt[b];
        if (v) lnext[b] = ((grp << 9) + b) * CAPG + atomicAdd(&gcur[(grp << 9) + b], v);
    }
    __syncthreads();
    #pragma unroll
    for (int i = 0; i < 8; ++i) {
        if (dr[i] >= 0) {
            int p = atomicAdd(&lnext[dr[i] >> 8], 1);
            pairs[p] = sr[i] | ((dr[i] & 255) << 17);
        }
    }
}

// ---------------- CSR phase B + GEMM1 fused; G written in SLICE layout ----------------
// Gs[s][node] (uint4 = 8 bf16 of channels 8s..8s+7); slice = 1.6MB, L2-resident
// for the slice-parallel gather.
__global__ __launch_bounds__(256) void slab_gemm1(const int* __restrict__ pairs,
                                                  const int* __restrict__ gcur,
                                                  const float* __restrict__ X,
                                                  const uint4* __restrict__ WP,
                                                  int* __restrict__ esrc,
                                                  int* __restrict__ cnt,
                                                  float* __restrict__ dinv,
                                                  uint4* __restrict__ G4s) {
    __shared__ int lc[256];
    __shared__ float ldv[256];
    __shared__ __align__(16) unsigned short Ls[4][16][64];
    int b = blockIdx.x;
    int t = threadIdx.x;
    lc[t] = 0;
    __syncthreads();
    #pragma unroll
    for (int g = 0; g < 8; ++g) {
        int rid = (g << 9) + b;
        int e0 = rid * CAPG;
        int n = min(gcur[rid], CAPG);
        for (int i0 = t * 4; i0 < n; i0 += 1024) {
            int4 w4 = *(const int4*)&pairs[e0 + i0];   // CAPG%4==0: in-region int4
            int wv[4] = {w4.x, w4.y, w4.z, w4.w};
            #pragma unroll
            for (int k = 0; k < 4; ++k) {
                if (i0 + k < n) {
                    int w = wv[k];
                    int li = w >> 17;
                    int p = atomicAdd(&lc[li], 1);
                    if (p < NCAP - 1) esrc[(((b << 8) + li) << 6) + p] = w & 0x1FFFF;
                }
            }
        }
    }
    __syncthreads();
    {
        int node = (b << 8) + t;
        if (node < NN) {
            int c = lc[t];
            int cc = min(c, NCAP - 1);
            esrc[(node << 6) + cc] = node;      // self-loop folded in as last entry
            cnt[node] = cc + 1;                 // incl. self
            float dv = rsqrtf((float)c + 1.0f);
            dinv[node] = dv;
            ldv[t] = dv;
        }
    }
    __syncthreads();

    // ---- gemm1 for this bucket: wave w handles tiles 4w..4w+3 ----
    int wave = t >> 6, lane = t & 63;
    int r = lane & 15, g = lane >> 4;
    #pragma unroll
    for (int ti = 0; ti < 4; ++ti) {
        int T = wave * 4 + ti;
        int node0 = (b << 8) + T * 16;
        if (node0 < NN) {                        // NN%16==0: tile all-valid
            const float* xr = X + (size_t)(node0 + r) * 64 + g * 8;
            float4 x0a = *(const float4*)(xr);
            float4 x0b = *(const float4*)(xr + 4);
            float4 x1a = *(const float4*)(xr + 32);
            float4 x1b = *(const float4*)(xr + 36);
            short8 ah0, al0, ah1, al1;
            split8(x0a, x0b, ah0, al0);
            split8(x1a, x1b, ah1, al1);
            f32x4 acc[4];
            #pragma unroll
            for (int c = 0; c < 4; ++c) acc[c] = (f32x4){0.f, 0.f, 0.f, 0.f};
            #pragma unroll
            for (int c = 0; c < 4; ++c) {
                short8 bh0 = as_s8(WP[(c * 2 + 0) * 64 + lane]);
                short8 bl0 = as_s8(WP[512 + (c * 2 + 0) * 64 + lane]);
                short8 bh1 = as_s8(WP[(c * 2 + 1) * 64 + lane]);
                short8 bl1 = as_s8(WP[512 + (c * 2 + 1) * 64 + lane]);
                acc[c] = mfma16(ah0, bh0, acc[c]);
                acc[c] = mfma16(al0, bh0, acc[c]);
                acc[c] = mfma16(ah0, bl0, acc[c]);
                acc[c] = mfma16(ah1, bh1, acc[c]);
                acc[c] = mfma16(al1, bh1, acc[c]);
                acc[c] = mfma16(ah1, bl1, acc[c]);
            }
            float dd[4];
            #pragma unroll
            for (int rr = 0; rr < 4; ++rr) dd[rr] = ldv[T * 16 + g * 4 + rr];
            #pragma unroll
            for (int c = 0; c < 4; ++c) {
                #pragma unroll
                for (int rr = 0; rr < 4; ++rr)
                    Ls[wave][g * 4 + rr][c * 16 + r] = f2bf(acc[c][rr] * dd[rr]);
            }
            // slice-layout write: 16 consecutive lanes -> 256B run in one slice
            #pragma unroll
            for (int i = 0; i < 2; ++i) {
                int idx = lane + i * 64;
                int u = idx >> 4, row = idx & 15;
                G4s[(size_t)u * NN + node0 + row] = *(const uint4*)&Ls[wave][row][u * 8];
            }
        }
    }
}

// ---------------- W pre-pack into B-fragment order (hi/lo split) + gcur zero ----------------
__global__ void wpack(const float* __restrict__ W1, const float* __restrict__ W2,
                      uint4* __restrict__ P, int* __restrict__ gcur) {
    int tid = blockIdx.x * blockDim.x + threadIdx.x;   // 0..1023
    if (tid >= 1024) return;
    ((uint4*)gcur)[tid] = make_uint4(0, 0, 0, 0);      // 4096 ints
    int w = tid >> 9;
    int f = tid & 511;
    int c = f >> 7;
    int t = (f >> 6) & 1;
    int lane = f & 63;
    const float* W = w ? W2 : W1;
    int k0 = t * 32 + (lane >> 4) * 8;
    int n  = c * 16 + (lane & 15);
    unsigned sh[8], sl[8];
    #pragma unroll
    for (int j = 0; j < 8; ++j) {
        float v = W[(k0 + j) * 64 + n];
        sh[j] = f2bf(v);
        sl[j] = f2bf(v - bflo(sh[j]));
    }
    uint4 ph, pl;
    ph.x = sh[0] | (sh[1] << 16); ph.y = sh[2] | (sh[3] << 16);
    ph.z = sh[4] | (sh[5] << 16); ph.w = sh[6] | (sh[7] << 16);
    pl.x = sl[0] | (sl[1] << 16); pl.y = sl[2] | (sl[3] << 16);
    pl.z = sl[4] | (sl[5] << 16); pl.w = sl[6] | (sl[7] << 16);
    P[w * 1024 + f]       = ph;
    P[w * 1024 + 512 + f] = pl;
}

// ---------------- GEMM2: A from slice-layout H1s, G2 written slice-layout ----------------
__global__ __launch_bounds__(256) void gemm2_mfma(const uint4* __restrict__ H1s,
                                                  const uint4* __restrict__ WP,
                                                  const float* __restrict__ dinv,
                                                  uint4* __restrict__ G4s) {
    __shared__ __align__(16) unsigned short Ls[4][16][64];
    int wave = threadIdx.x >> 6, lane = threadIdx.x & 63;
    int tile = blockIdx.x * 4 + wave;
    bool active = tile < (NN / 16);
    int node0 = (active ? tile : 0) * 16;
    int r = lane & 15, g = lane >> 4;

    // channels g*8..g*8+7 = slice g (t=0); 32+g*8.. = slice 4+g (t=1)
    short8 a0 = as_s8(H1s[(size_t)g * NN + node0 + r]);
    short8 a1 = as_s8(H1s[(size_t)(4 + g) * NN + node0 + r]);

    f32x4 acc[4];
    #pragma unroll
    for (int c = 0; c < 4; ++c) acc[c] = (f32x4){0.f, 0.f, 0.f, 0.f};
    #pragma unroll
    for (int c = 0; c < 4; ++c) {
        short8 bh0 = as_s8(WP[(c * 2 + 0) * 64 + lane]);
        short8 bl0 = as_s8(WP[512 + (c * 2 + 0) * 64 + lane]);
        short8 bh1 = as_s8(WP[(c * 2 + 1) * 64 + lane]);
        short8 bl1 = as_s8(WP[512 + (c * 2 + 1) * 64 + lane]);
        acc[c] = mfma16(a0, bh0, acc[c]);
        acc[c] = mfma16(a0, bl0, acc[c]);
        acc[c] = mfma16(a1, bh1, acc[c]);
        acc[c] = mfma16(a1, bl1, acc[c]);
    }
    float dd[4];
    #pragma unroll
    for (int rr = 0; rr < 4; ++rr) dd[rr] = dinv[node0 + g * 4 + rr];
    #pragma unroll
    for (int c = 0; c < 4; ++c) {
        #pragma unroll
        for (int rr = 0; rr < 4; ++rr)
            Ls[wave][g * 4 + rr][c * 16 + r] = f2bf(acc[c][rr] * dd[rr]);
    }
    if (active) {
        #pragma unroll
        for (int i = 0; i < 2; ++i) {
            int idx = lane + i * 64;
            int u = idx >> 4, row = idx & 15;
            G4s[(size_t)u * NN + node0 + row] = *(const uint4*)&Ls[wave][row][u * 8];
        }
    }
}

// accumulate one bf16x8 row fragment into a0..a7
#define ACC8(u) do { \
    a0 += bflo((u).x); a1 += bfhi((u).x); a2 += bflo((u).y); a3 += bfhi((u).y); \
    a4 += bflo((u).z); a5 += bfhi((u).z); a6 += bflo((u).w); a7 += bfhi((u).w); } while (0)

// ---------------- slice-parallel gather: agg(8ch) + bias + relu -> Hs ----------------
// slice = blockIdx & 7 -> (round-robin) one XCD per slice; slice = 1.6MB,
// L2-resident; random G reads become L2 hits. esrc/cnt/dinv are streamed.
// Slab includes self, so the loop is uniform. 16 lanes per node.
__global__ __launch_bounds__(256) void gather_slice(
        const int* __restrict__ cnt, const int* __restrict__ esrc,
        const float* __restrict__ dinv, const uint4* __restrict__ Gs,
        const float* __restrict__ bias, uint4* __restrict__ Hs) {
    int blk = blockIdx.x;
    int s = blk & 7;
    int nblk = blk >> 3;
    int lane = threadIdx.x & 63;
    int n = lane >> 4, l = lane & 15;
    int node = nblk * 16 + (threadIdx.x >> 6) * 4 + n;   // NN%16==0
    const uint4* Gb = Gs + (size_t)s * NN;
    int cn = cnt[node];
    int base = node << 6;
    float a0 = 0.f, a1 = 0.f, a2 = 0.f, a3 = 0.f,
          a4 = 0.f, a5 = 0.f, a6 = 0.f, a7 = 0.f;
    for (int j = base + l, jend = base + cn; j < jend; j += 16) {
        uint4 u = Gb[esrc[j]];
        ACC8(u);
    }
    #pragma unroll
    for (int off = 1; off < 16; off <<= 1) {
        a0 += __shfl_xor(a0, off); a1 += __shfl_xor(a1, off);
        a2 += __shfl_xor(a2, off); a3 += __shfl_xor(a3, off);
        a4 += __shfl_xor(a4, off); a5 += __shfl_xor(a5, off);
        a6 += __shfl_xor(a6, off); a7 += __shfl_xor(a7, off);
    }
    if (l == 0) {
        float dd = dinv[node];
        float4 b0 = ((const float4*)bias)[2 * s];
        float4 b1v = ((const float4*)bias)[2 * s + 1];
        float h0 = fmaxf(fmaf(a0, dd, b0.x), 0.f);
        float h1 = fmaxf(fmaf(a1, dd, b0.y), 0.f);
        float h2 = fmaxf(fmaf(a2, dd, b0.z), 0.f);
        float h3 = fmaxf(fmaf(a3, dd, b0.w), 0.f);
        float h4 = fmaxf(fmaf(a4, dd, b1v.x), 0.f);
        float h5 = fmaxf(fmaf(a5, dd, b1v.y), 0.f);
        float h6 = fmaxf(fmaf(a6, dd, b1v.z), 0.f);
        float h7 = fmaxf(fmaf(a7, dd, b1v.w), 0.f);
        uint4 pk;
        pk.x = (unsigned)f2bf(h0) | ((unsigned)f2bf(h1) << 16);
        pk.y = (unsigned)f2bf(h2) | ((unsigned)f2bf(h3) << 16);
        pk.z = (unsigned)f2bf(h4) | ((unsigned)f2bf(h5) << 16);
        pk.w = (unsigned)f2bf(h6) | ((unsigned)f2bf(h7) << 16);
        Hs[(size_t)s * NN + node] = pk;
    }
}

// ---------------- FC: out = h2 @ Wfc + bfc (h2 in slice layout, streaming) ----------------
__global__ __launch_bounds__(256) void fc_out(const uint4* __restrict__ H2s,
                                              const float* __restrict__ Wfc,
                                              const float* __restrict__ bfc,
                                              float* __restrict__ out) {
    int wave = threadIdx.x >> 6, lane = threadIdx.x & 63;
    int q = lane >> 4, c = lane & 15;
    float Wreg[16];
    #pragma unroll
    for (int i = 0; i < 16; ++i) Wreg[i] = Wfc[(q * 16 + i) * 16 + c];
    int node0 = (blockIdx.x * 4 + wave) * 4;
    #pragma unroll
    for (int nd = 0; nd < 4; ++nd) {
        int node = node0 + nd;
        uint4 ua = H2s[(size_t)(2 * q) * NN + node];       // ch 16q..16q+7
        uint4 ub = H2s[(size_t)(2 * q + 1) * NN + node];   // ch 16q+8..16q+15
        float acc = 0.f;
        acc = fmaf(bflo(ua.x), Wreg[0], acc);
        acc = fmaf(bfhi(ua.x), Wreg[1], acc);
        acc = fmaf(bflo(ua.y), Wreg[2], acc);
        acc = fmaf(bfhi(ua.y), Wreg[3], acc);
        acc = fmaf(bflo(ua.z), Wreg[4], acc);
        acc = fmaf(bfhi(ua.z), Wreg[5], acc);
        acc = fmaf(bflo(ua.w), Wreg[6], acc);
        acc = fmaf(bfhi(ua.w), Wreg[7], acc);
        acc = fmaf(bflo(ub.x), Wreg[8], acc);
        acc = fmaf(bfhi(ub.x), Wreg[9], acc);
        acc = fmaf(bflo(ub.y), Wreg[10], acc);
        acc = fmaf(bfhi(ub.y), Wreg[11], acc);
        acc = fmaf(bflo(ub.z), Wreg[12], acc);
        acc = fmaf(bfhi(ub.z), Wreg[13], acc);
        acc = fmaf(bflo(ub.w), Wreg[14], acc);
        acc = fmaf(bfhi(ub.w), Wreg[15], acc);
        acc += __shfl_xor(acc, 16);
        acc += __shfl_xor(acc, 32);
        if (lane < 16) out[node * 16 + c] = acc + bfc[c];
    }
}

extern "C" void kernel_launch(void* const* d_in, const int* in_sizes, int n_in,
                              void* d_out, int out_size, void* d_ws, size_t ws_size,
                              hipStream_t stream) {
    const float* x   = (const float*)d_in[0];
    const int*   ei  = (const int*)d_in[1];
    const float* W1  = (const float*)d_in[2];
    const float* b1  = (const float*)d_in[3];
    const float* W2  = (const float*)d_in[4];
    const float* b2  = (const float*)d_in[5];
    const float* Wfc = (const float*)d_in[6];
    const float* bfc = (const float*)d_in[7];
    float* out = (float*)d_out;

    const int* src = ei;
    const int* dst = ei + NE;

    // ws: gcur[4096] | cnt[NN] | dinv[NN] | esrc[NN*64 25.6MB]
    //     | A: G slices (12.8MB, G1s then G2s) | B: pairs -> H1s -> H2s (12.8MB)
    //     | WPK[2048 uint4, 32KB]
    // aliasing: pairs dead after slab_gemm1, H1s written by gather1 after;
    // H1s dead after gemm2, H2s written by gather2 after; G1s dead after
    // gather1, G2s written by gemm2 after.
    int*      gcur  = (int*)d_ws;
    int*      cnt   = gcur + 4096;
    float*    dinvp = (float*)(cnt + NN);
    int*      esrc  = (int*)(dinvp + NN);
    uint4*    A     = (uint4*)(esrc + (size_t)NN * NCAP);
    uint4*    B     = A + (size_t)NN * 8;
    uint4*    WPK   = B + (size_t)NN * 8;
    int*      pairs = (int*)B;

    // ---- CSR build: wpack (zeroes gcur) -> two-pass bin -> slab+gemm1 (slice G) ----
    wpack<<<4, 256, 0, stream>>>(W1, W2, WPK, gcur);
    bin_edges<<<NCHUNK, 256, 0, stream>>>(src, dst, gcur, pairs);
    slab_gemm1<<<NB, 256, 0, stream>>>(pairs, gcur, x, WPK, esrc, cnt, dinvp, A);

    // ---- layer 1: slice-parallel gather -> H1s ----
    gather_slice<<<(NN / 16) * 8, 256, 0, stream>>>(cnt, esrc, dinvp, A, b1, B);

    // ---- layer 2: gemm2 (slice in/out) -> G2s ; slice gather -> H2s (in-place over H1s) ----
    gemm2_mfma<<<(NN / 16 + 3) / 4, 256, 0, stream>>>(B, WPK + 1024, dinvp, A);
    gather_slice<<<(NN / 16) * 8, 256, 0, stream>>>(cnt, esrc, dinvp, A, b2, B);

    // ---- FC -> out ----
    fc_out<<<NN / 16, 256, 0, stream>>>(B, Wfc, bfc, out);
}

// Round 11
// 226.203 us; speedup vs baseline: 1.3726x; 1.3726x over previous
//
#include <hip/hip_runtime.h>

#define NN 100000
#define NE 1600000
#define NCAP 64             // per-node slab capacity (incl. self); deg ~ Poisson(16)
#define NB2 782             // buckets of 128 dst-nodes
#define NBP2 1024           // padded bucket count
#define CAPG 384            // per-(grp,bucket) capacity: mean 257, sigma~16 -> 8 sigma
#define CHUNK 2048
#define NCHUNK 782          // ceil(NE/CHUNK)

typedef __attribute__((ext_vector_type(8))) short short8;   // 8 bf16 (4 VGPRs)
typedef __attribute__((ext_vector_type(4))) float f32x4;    // MFMA 16x16 accumulator

static __device__ __forceinline__ unsigned short f2bf(float f) {
    unsigned u = __float_as_uint(f);
    u += 0x7fffu + ((u >> 16) & 1u);   // RNE
    return (unsigned short)(u >> 16);
}
static __device__ __forceinline__ float bflo(unsigned u) { return __uint_as_float(u << 16); }
static __device__ __forceinline__ float bfhi(unsigned u) { return __uint_as_float(u & 0xffff0000u); }

static __device__ __forceinline__ short8 as_s8(uint4 u) {
    union { uint4 u4; short8 s8; } x; x.u4 = u; return x.s8;
}
static __device__ __forceinline__ f32x4 mfma16(short8 a, short8 b, f32x4 c) {
    return __builtin_amdgcn_mfma_f32_16x16x32_bf16(a, b, c, 0, 0, 0);
}

// split 8 fp32 into hi/lo bf16x8 fragments (hi = RNE(v), lo = RNE(v - hi))
static __device__ __forceinline__ void split8(float4 a, float4 b, short8& hi8, short8& lo8) {
    float vv[8] = {a.x, a.y, a.z, a.w, b.x, b.y, b.z, b.w};
    unsigned h[8], l[8];
    #pragma unroll
    for (int j = 0; j < 8; ++j) {
        h[j] = f2bf(vv[j]);
        l[j] = f2bf(vv[j] - bflo(h[j]));
    }
    uint4 uh, ul;
    uh.x = h[0] | (h[1] << 16); uh.y = h[2] | (h[3] << 16);
    uh.z = h[4] | (h[5] << 16); uh.w = h[6] | (h[7] << 16);
    ul.x = l[0] | (l[1] << 16); ul.y = l[2] | (l[3] << 16);
    ul.z = l[4] | (l[5] << 16); ul.w = l[6] | (l[7] << 16);
    hi8 = as_s8(uh); lo8 = as_s8(ul);
}

// ---------------- CSR build phase A ----------------
// Bin edges into per-group bucket regions as packed (src | local_dst<<17) runs.
// grp = blockIdx.x & 7 privatizes write regions to (heuristically) one XCD each.
__global__ __launch_bounds__(256) void bin_edges(const int* __restrict__ src,
                                                 const int* __restrict__ dst,
                                                 int* __restrict__ gcur,
                                                 int* __restrict__ pairs) {
    __shared__ int lcnt[NBP2];
    __shared__ int lnext[NBP2];
    int t = threadIdx.x;
    int grp = blockIdx.x & 7;
    #pragma unroll
    for (int i = 0; i < 4; ++i) lcnt[t + 256 * i] = 0;
    __syncthreads();
    int base = blockIdx.x * CHUNK;
    int sr[8], dr[8];
    #pragma unroll
    for (int i = 0; i < 8; ++i) {
        int e = base + t + 256 * i;
        bool v = e < NE;
        sr[i] = v ? src[e] : 0;
        dr[i] = v ? dst[e] : -1;
        if (v) atomicAdd(&lcnt[dr[i] >> 7], 1);
    }
    __syncthreads();
    #pragma unroll
    for (int i = 0; i < 4; ++i) {
        int b = t + 256 * i;
        int v = lcnt[b];
        if (v) lnext[b] = ((grp << 10) + b) * CAPG + atomicAdd(&gcur[(grp << 10) + b], v);
    }
    __syncthreads();
    #pragma unroll
    for (int i = 0; i < 8; ++i) {
        if (dr[i] >= 0) {
            int p = atomicAdd(&lnext[dr[i] >> 7], 1);
            pairs[p] = sr[i] | ((dr[i] & 127) << 17);
        }
    }
}

// ---------------- CSR phase B + GEMM1 fused ----------------
// Block b: (1) scatter bucket b's 8 group segments into its 32KB slab window,
// self-append, cnt/dinv (dinv kept in LDS); (2) gemm1 for its own 128 nodes
// (2 tiles per wave), G = bf16((x@W1)*dinv).
__global__ __launch_bounds__(256) void slab_gemm1(const int* __restrict__ pairs,
                                                  const int* __restrict__ gcur,
                                                  const float* __restrict__ X,
                                                  const uint4* __restrict__ WP,
                                                  int* __restrict__ esrc,
                                                  int* __restrict__ cnt,
                                                  float* __restrict__ dinv,
                                                  uint4* __restrict__ G4) {
    __shared__ int lc[128];
    __shared__ float ldv[128];
    __shared__ __align__(16) unsigned short Ls[4][16][64];
    int b = blockIdx.x;
    int t = threadIdx.x;
    if (t < 128) lc[t] = 0;
    __syncthreads();
    #pragma unroll
    for (int g = 0; g < 8; ++g) {
        int rid = (g << 10) + b;
        int e0 = rid * CAPG;
        int n = min(gcur[rid], CAPG);
        for (int i0 = t * 4; i0 < n; i0 += 1024) {
            int4 w4 = *(const int4*)&pairs[e0 + i0];   // region allocated to CAPG, aligned
            int wv[4] = {w4.x, w4.y, w4.z, w4.w};
            #pragma unroll
            for (int k = 0; k < 4; ++k) {
                if (i0 + k < n) {
                    int w = wv[k];
                    int li = w >> 17;
                    int p = atomicAdd(&lc[li], 1);
                    if (p < NCAP - 1) esrc[(((b << 7) + li) << 6) + p] = w & 0x1FFFF;
                }
            }
        }
    }
    __syncthreads();
    if (t < 128) {
        int node = (b << 7) + t;
        if (node < NN) {
            int c = lc[t];
            int cc = min(c, NCAP - 1);
            esrc[(node << 6) + cc] = node;      // self-loop folded in as last entry
            cnt[node] = cc + 1;                 // incl. self
            float dv = rsqrtf((float)c + 1.0f);
            dinv[node] = dv;
            ldv[t] = dv;
        }
    }
    __syncthreads();

    // ---- gemm1 for this bucket: wave w handles tiles 2w, 2w+1 ----
    int wave = t >> 6, lane = t & 63;
    int r = lane & 15, g = lane >> 4;
    #pragma unroll
    for (int ti = 0; ti < 2; ++ti) {
        int T = wave * 2 + ti;
        int node0 = (b << 7) + T * 16;
        if (node0 < NN) {                        // NN%16==0: tile all-valid
            const float* xr = X + (size_t)(node0 + r) * 64 + g * 8;
            float4 x0a = *(const float4*)(xr);
            float4 x0b = *(const float4*)(xr + 4);
            float4 x1a = *(const float4*)(xr + 32);
            float4 x1b = *(const float4*)(xr + 36);
            short8 ah0, al0, ah1, al1;
            split8(x0a, x0b, ah0, al0);
            split8(x1a, x1b, ah1, al1);
            f32x4 acc[4];
            #pragma unroll
            for (int c = 0; c < 4; ++c) acc[c] = (f32x4){0.f, 0.f, 0.f, 0.f};
            #pragma unroll
            for (int c = 0; c < 4; ++c) {
                short8 bh0 = as_s8(WP[(c * 2 + 0) * 64 + lane]);
                short8 bl0 = as_s8(WP[512 + (c * 2 + 0) * 64 + lane]);
                short8 bh1 = as_s8(WP[(c * 2 + 1) * 64 + lane]);
                short8 bl1 = as_s8(WP[512 + (c * 2 + 1) * 64 + lane]);
                acc[c] = mfma16(ah0, bh0, acc[c]);
                acc[c] = mfma16(al0, bh0, acc[c]);
                acc[c] = mfma16(ah0, bl0, acc[c]);
                acc[c] = mfma16(ah1, bh1, acc[c]);
                acc[c] = mfma16(al1, bh1, acc[c]);
                acc[c] = mfma16(ah1, bl1, acc[c]);
            }
            float dd[4];
            #pragma unroll
            for (int rr = 0; rr < 4; ++rr) dd[rr] = ldv[T * 16 + g * 4 + rr];
            // wave-private Ls quadrant: no barrier needed (compiler lgkmcnt)
            #pragma unroll
            for (int c = 0; c < 4; ++c) {
                #pragma unroll
                for (int rr = 0; rr < 4; ++rr)
                    Ls[wave][g * 4 + rr][c * 16 + r] = f2bf(acc[c][rr] * dd[rr]);
            }
            #pragma unroll
            for (int i = 0; i < 2; ++i) {
                int idx = lane + i * 64;
                int row = idx >> 3, u = idx & 7;
                G4[(size_t)(node0 + row) * 8 + u] = *(const uint4*)&Ls[wave][row][u * 8];
            }
        }
    }
}

// ---------------- W pre-pack into B-fragment order (hi/lo split) + gcur zero ----------------
__global__ void wpack(const float* __restrict__ W1, const float* __restrict__ W2,
                      uint4* __restrict__ P, int* __restrict__ gcur) {
    int tid = blockIdx.x * blockDim.x + threadIdx.x;   // 0..1023
    if (tid >= 1024) return;
    #pragma unroll
    for (int k = 0; k < 8; ++k) gcur[tid + 1024 * k] = 0;
    int w = tid >> 9;
    int f = tid & 511;
    int c = f >> 7;
    int t = (f >> 6) & 1;
    int lane = f & 63;
    const float* W = w ? W2 : W1;
    int k0 = t * 32 + (lane >> 4) * 8;
    int n  = c * 16 + (lane & 15);
    unsigned sh[8], sl[8];
    #pragma unroll
    for (int j = 0; j < 8; ++j) {
        float v = W[(k0 + j) * 64 + n];
        sh[j] = f2bf(v);
        sl[j] = f2bf(v - bflo(sh[j]));
    }
    uint4 ph, pl;
    ph.x = sh[0] | (sh[1] << 16); ph.y = sh[2] | (sh[3] << 16);
    ph.z = sh[4] | (sh[5] << 16); ph.w = sh[6] | (sh[7] << 16);
    pl.x = sl[0] | (sl[1] << 16); pl.y = sl[2] | (sl[3] << 16);
    pl.z = sl[4] | (sl[5] << 16); pl.w = sl[6] | (sl[7] << 16);
    P[w * 1024 + f]       = ph;
    P[w * 1024 + 512 + f] = pl;
}

// ---------------- GEMM2 (bf16 h1, W split MFMA): G = bf16((h1@W2)*dinv) ----------------
__global__ __launch_bounds__(256) void gemm2_mfma(const uint4* __restrict__ X4,
                                                  const uint4* __restrict__ WP,
                                                  const float* __restrict__ dinv,
                                                  uint4* __restrict__ G4) {
    __shared__ __align__(16) unsigned short Ls[4][16][64];
    int wave = threadIdx.x >> 6, lane = threadIdx.x & 63;
    int tile = blockIdx.x * 4 + wave;
    bool active = tile < (NN / 16);
    int node0 = (active ? tile : 0) * 16;
    int r = lane & 15, g = lane >> 4;

    short8 a0 = as_s8(X4[(size_t)(node0 + r) * 8 + g]);
    short8 a1 = as_s8(X4[(size_t)(node0 + r) * 8 + 4 + g]);

    f32x4 acc[4];
    #pragma unroll
    for (int c = 0; c < 4; ++c) acc[c] = (f32x4){0.f, 0.f, 0.f, 0.f};
    #pragma unroll
    for (int c = 0; c < 4; ++c) {
        short8 bh0 = as_s8(WP[(c * 2 + 0) * 64 + lane]);
        short8 bl0 = as_s8(WP[512 + (c * 2 + 0) * 64 + lane]);
        short8 bh1 = as_s8(WP[(c * 2 + 1) * 64 + lane]);
        short8 bl1 = as_s8(WP[512 + (c * 2 + 1) * 64 + lane]);
        acc[c] = mfma16(a0, bh0, acc[c]);
        acc[c] = mfma16(a0, bl0, acc[c]);
        acc[c] = mfma16(a1, bh1, acc[c]);
        acc[c] = mfma16(a1, bl1, acc[c]);
    }
    float dd[4];
    #pragma unroll
    for (int rr = 0; rr < 4; ++rr) dd[rr] = dinv[node0 + g * 4 + rr];
    // wave-private Ls quadrant: no barrier needed
    #pragma unroll
    for (int c = 0; c < 4; ++c) {
        #pragma unroll
        for (int rr = 0; rr < 4; ++rr)
            Ls[wave][g * 4 + rr][c * 16 + r] = f2bf(acc[c][rr] * dd[rr]);
    }
    if (active) {
        #pragma unroll
        for (int i = 0; i < 2; ++i) {
            int idx = lane + i * 64;
            int row = idx >> 3, u = idx & 7;
            G4[(size_t)(node0 + row) * 8 + u] = *(const uint4*)&Ls[wave][row][u * 8];
        }
    }
}

// accumulate one bf16x8 row fragment into a0..a7
#define ACC8(u) do { \
    a0 += bflo((u).x); a1 += bfhi((u).x); a2 += bflo((u).y); a3 += bfhi((u).y); \
    a4 += bflo((u).z); a5 += bfhi((u).z); a6 += bflo((u).w); a7 += bfhi((u).w); } while (0)

// gather core (R2 loop form): slab is self-inclusive, esrc[j] is an 8-lane
// broadcast, two independent G reads in flight per iter.
#define GATHER_CORE(node)                                                     \
    int j0 = (node) << 6;                                                     \
    int e1 = j0 + cnt[node];                                                  \
    float a0 = 0.f, a1 = 0.f, a2 = 0.f, a3 = 0.f,                             \
          a4 = 0.f, a5 = 0.f, a6 = 0.f, a7 = 0.f;                             \
    int j = j0 + e;                                                           \
    for (; j + 8 < e1; j += 16) {                                             \
        int s0 = esrc[j], s1 = esrc[j + 8];                                   \
        uint4 u0 = G4[s0 * 8 + m];                                            \
        uint4 u1 = G4[s1 * 8 + m];                                            \
        ACC8(u0); ACC8(u1);                                                   \
    }                                                                         \
    for (; j < e1; j += 8) {                                                  \
        uint4 u = G4[esrc[j] * 8 + m];                                        \
        ACC8(u);                                                              \
    }                                                                         \
    a0 += __shfl_xor(a0, 8);  a1 += __shfl_xor(a1, 8);                        \
    a2 += __shfl_xor(a2, 8);  a3 += __shfl_xor(a3, 8);                        \
    a4 += __shfl_xor(a4, 8);  a5 += __shfl_xor(a5, 8);                        \
    a6 += __shfl_xor(a6, 8);  a7 += __shfl_xor(a7, 8);                        \
    a0 += __shfl_xor(a0, 16); a1 += __shfl_xor(a1, 16);                       \
    a2 += __shfl_xor(a2, 16); a3 += __shfl_xor(a3, 16);                       \
    a4 += __shfl_xor(a4, 16); a5 += __shfl_xor(a5, 16);                       \
    a6 += __shfl_xor(a6, 16); a7 += __shfl_xor(a7, 16);                       \
    a0 += __shfl_xor(a0, 32); a1 += __shfl_xor(a1, 32);                       \
    a2 += __shfl_xor(a2, 32); a3 += __shfl_xor(a3, 32);                       \
    a4 += __shfl_xor(a4, 32); a5 += __shfl_xor(a5, 32);                       \
    a6 += __shfl_xor(a6, 32); a7 += __shfl_xor(a7, 32);

// ---------------- gather-1: agg (incl. self) + bias + relu -> bf16 h1 ----------------
__global__ __launch_bounds__(256) void gather_bf16(
        const int* __restrict__ cnt, const int* __restrict__ esrc,
        const float* __restrict__ dinv, const uint4* __restrict__ G4,
        const float* __restrict__ b, uint4* __restrict__ outH) {
    int node = blockIdx.x * 4 + (threadIdx.x >> 6);
    int lane = threadIdx.x & 63;
    int e = lane >> 3, m = lane & 7;
    GATHER_CORE(node)
    if (e == 0) {
        float dd = dinv[node];
        float4 b0 = ((const float4*)b)[2 * m];
        float4 b1v = ((const float4*)b)[2 * m + 1];
        float h0 = fmaxf(fmaf(a0, dd, b0.x), 0.f);
        float h1 = fmaxf(fmaf(a1, dd, b0.y), 0.f);
        float h2 = fmaxf(fmaf(a2, dd, b0.z), 0.f);
        float h3 = fmaxf(fmaf(a3, dd, b0.w), 0.f);
        float h4 = fmaxf(fmaf(a4, dd, b1v.x), 0.f);
        float h5 = fmaxf(fmaf(a5, dd, b1v.y), 0.f);
        float h6 = fmaxf(fmaf(a6, dd, b1v.z), 0.f);
        float h7 = fmaxf(fmaf(a7, dd, b1v.w), 0.f);
        uint4 pk;
        pk.x = (unsigned)f2bf(h0) | ((unsigned)f2bf(h1) << 16);
        pk.y = (unsigned)f2bf(h2) | ((unsigned)f2bf(h3) << 16);
        pk.z = (unsigned)f2bf(h4) | ((unsigned)f2bf(h5) << 16);
        pk.w = (unsigned)f2bf(h6) | ((unsigned)f2bf(h7) << 16);
        outH[(size_t)node * 8 + m] = pk;
    }
}

// ---------------- gather-2 + FC fused ----------------
__global__ __launch_bounds__(256) void gather_fc(
        const int* __restrict__ cnt, const int* __restrict__ esrc,
        const float* __restrict__ dinv, const uint4* __restrict__ G4,
        const float* __restrict__ b2, const float* __restrict__ Wfc,
        const float* __restrict__ bfc, float* __restrict__ out) {
    int node = blockIdx.x * 4 + (threadIdx.x >> 6);
    int lane = threadIdx.x & 63;
    int e = lane >> 3, m = lane & 7;
    int q = lane >> 4, c = lane & 15;    // FC roles
    float Wreg[16];
    #pragma unroll
    for (int i = 0; i < 16; ++i) Wreg[i] = Wfc[(q * 16 + i) * 16 + c];
    GATHER_CORE(node)
    float dd = dinv[node];
    float4 b0 = ((const float4*)b2)[2 * m];
    float4 b1v = ((const float4*)b2)[2 * m + 1];
    a0 = fmaxf(fmaf(a0, dd, b0.x), 0.f);
    a1 = fmaxf(fmaf(a1, dd, b0.y), 0.f);
    a2 = fmaxf(fmaf(a2, dd, b0.z), 0.f);
    a3 = fmaxf(fmaf(a3, dd, b0.w), 0.f);
    a4 = fmaxf(fmaf(a4, dd, b1v.x), 0.f);
    a5 = fmaxf(fmaf(a5, dd, b1v.y), 0.f);
    a6 = fmaxf(fmaf(a6, dd, b1v.z), 0.f);
    a7 = fmaxf(fmaf(a7, dd, b1v.w), 0.f);
    int sl0 = 2 * q, sl1 = 2 * q + 1;
    float acc = 0.f;
    acc = fmaf(__shfl(a0, sl0), Wreg[0], acc);
    acc = fmaf(__shfl(a1, sl0), Wreg[1], acc);
    acc = fmaf(__shfl(a2, sl0), Wreg[2], acc);
    acc = fmaf(__shfl(a3, sl0), Wreg[3], acc);
    acc = fmaf(__shfl(a4, sl0), Wreg[4], acc);
    acc = fmaf(__shfl(a5, sl0), Wreg[5], acc);
    acc = fmaf(__shfl(a6, sl0), Wreg[6], acc);
    acc = fmaf(__shfl(a7, sl0), Wreg[7], acc);
    acc = fmaf(__shfl(a0, sl1), Wreg[8], acc);
    acc = fmaf(__shfl(a1, sl1), Wreg[9], acc);
    acc = fmaf(__shfl(a2, sl1), Wreg[10], acc);
    acc = fmaf(__shfl(a3, sl1), Wreg[11], acc);
    acc = fmaf(__shfl(a4, sl1), Wreg[12], acc);
    acc = fmaf(__shfl(a5, sl1), Wreg[13], acc);
    acc = fmaf(__shfl(a6, sl1), Wreg[14], acc);
    acc = fmaf(__shfl(a7, sl1), Wreg[15], acc);
    acc += __shfl_xor(acc, 16);
    acc += __shfl_xor(acc, 32);
    if (lane < 16) out[node * 16 + c] = acc + bfc[c];
}

extern "C" void kernel_launch(void* const* d_in, const int* in_sizes, int n_in,
                              void* d_out, int out_size, void* d_ws, size_t ws_size,
                              hipStream_t stream) {
    const float* x   = (const float*)d_in[0];
    const int*   ei  = (const int*)d_in[1];
    const float* W1  = (const float*)d_in[2];
    const float* b1  = (const float*)d_in[3];
    const float* W2  = (const float*)d_in[4];
    const float* b2  = (const float*)d_in[5];
    const float* Wfc = (const float*)d_in[6];
    const float* bfc = (const float*)d_in[7];
    float* out = (float*)d_out;

    const int* src = ei;
    const int* dst = ei + NE;

    // ws: gcur[8192] | cnt[NN] | dinv[NN] | esrc[NN*64 25.6MB] | G[NN*32 u, 12.8MB]
    //     | bufB[NN*64 bf16, 12.8MB] | WPK[2048 uint4, 32KB]
    // pairs (8*1024*384 ints = 12.58MB) aliases bufB (consumed by slab_gemm1
    // before gather-1 writes bufB)
    int*      gcur  = (int*)d_ws;
    int*      cnt   = gcur + 8192;
    float*    dinvp = (float*)(cnt + NN);
    int*      esrc  = (int*)(dinvp + NN);
    unsigned* G     = (unsigned*)(esrc + (size_t)NN * NCAP);
    uint4*    bufB  = (uint4*)(G + (size_t)NN * 32);
    uint4*    WPK   = (uint4*)((unsigned*)bufB + (size_t)NN * 32);
    int*      pairs = (int*)bufB;

    // ---- CSR build: wpack (zeroes gcur) -> two-pass bin (grp-private) -> slab+gemm1 ----
    wpack<<<4, 256, 0, stream>>>(W1, W2, WPK, gcur);
    bin_edges<<<NCHUNK, 256, 0, stream>>>(src, dst, gcur, pairs);
    slab_gemm1<<<NB2, 256, 0, stream>>>(pairs, gcur, x, WPK, esrc, cnt, dinvp, (uint4*)G);

    // ---- layer 1 gather -> bf16 h1 ----
    gather_bf16<<<NN / 4, 256, 0, stream>>>(cnt, esrc, dinvp, (const uint4*)G, b1, bufB);

    // ---- layer 2: gemm2 -> G ; gather + FC -> out ----
    gemm2_mfma<<<(NN / 16 + 3) / 4, 256, 0, stream>>>(bufB, WPK + 1024, dinvp, (uint4*)G);
    gather_fc<<<NN / 4, 256, 0, stream>>>(cnt, esrc, dinvp, (const uint4*)G, b2, Wfc, bfc, out);
}